// Round 8
// baseline (99066.571 us; speedup 1.0000x reference)
//
#include <hip/hip_runtime.h>
#include <cstdint>

// ---------------------------------------------------------------------------
// HierarchicalGraphMemoryNetwork on MI355X — round 8
//
// Scan (per wave: 256 gate rows = 16 MFMA tiles, K=256):
//  - tiles 0-7  : AGPR-pinned fragments (256 AGPRs)      [proven, round 6]
//  - tiles 12-15: LDS-resident fragments (128 KiB block) [round-7 path, now
//                 isolated: NO VGPR pins this round — round 7's NaN is
//                 attributed to 384 pinned regs starving regalloc]
//  - tiles 8-11 : streamed from L2 via volatile-asm global_load_dwordx4
//                 (proven, round 6), issued at TOP of step, consumed LAST
//                 after one vmcnt(0)+sched_barrier -> latency hidden under
//                 phases A-C (~1800cy). 128KB/step (round 6: 256KB + 2 drains).
// ---------------------------------------------------------------------------

#define T_LEN 8192
#define IN_F  256
#define HID   256
#define GATE  1024
#define NREL  4
#define OUT_N 256

typedef _Float16 f16x8 __attribute__((ext_vector_type(8)));
typedef float    f32x4 __attribute__((ext_vector_type(4)));
typedef uint32_t u32x4 __attribute__((ext_vector_type(4)));

__device__ __forceinline__ f32x4 mfma16(u32x4 a, u32x4 b, f32x4 c) {
  return __builtin_amdgcn_mfma_f32_16x16x32_f16(
      __builtin_bit_cast(f16x8, a), __builtin_bit_cast(f16x8, b), c, 0, 0, 0);
}

__device__ __forceinline__ float fsig(float x) { return 1.f / (1.f + __expf(-x)); }
__device__ __forceinline__ float ftanh(float x) { return 2.f / (1.f + __expf(-2.f * x)) - 1.f; }

// ------------------------------- GEMM --------------------------------------
__global__ __launch_bounds__(256) void gemm_kernel(
    const float* __restrict__ A, int lda,
    const float* __restrict__ W, int ldw,
    const float* __restrict__ bias,
    const float* addC,
    float* C, int ldc, int M, int N, int K) {
  __shared__ float As[16][64];
  __shared__ float Bs[16][64];
  const int tid = threadIdx.x;
  const int tx = tid & 15, ty = tid >> 4;
  const int m0 = blockIdx.y * 64, n0 = blockIdx.x * 64;
  const int lr = tid >> 2;
  const int lc = (tid & 3) * 4;
  float acc[4][4] = {};
  for (int k0 = 0; k0 < K; k0 += 16) {
    float4 av = *(const float4*)&A[(size_t)(m0 + lr) * lda + k0 + lc];
    float4 wv = *(const float4*)&W[(size_t)(n0 + lr) * ldw + k0 + lc];
    As[lc + 0][lr] = av.x; As[lc + 1][lr] = av.y; As[lc + 2][lr] = av.z; As[lc + 3][lr] = av.w;
    Bs[lc + 0][lr] = wv.x; Bs[lc + 1][lr] = wv.y; Bs[lc + 2][lr] = wv.z; Bs[lc + 3][lr] = wv.w;
    __syncthreads();
#pragma unroll
    for (int k = 0; k < 16; ++k) {
      float a[4], b[4];
#pragma unroll
      for (int i = 0; i < 4; ++i) a[i] = As[k][ty * 4 + i];
#pragma unroll
      for (int jj = 0; jj < 4; ++jj) b[jj] = Bs[k][tx * 4 + jj];
#pragma unroll
      for (int i = 0; i < 4; ++i)
#pragma unroll
        for (int jj = 0; jj < 4; ++jj) acc[i][jj] += a[i] * b[jj];
    }
    __syncthreads();
  }
#pragma unroll
  for (int i = 0; i < 4; ++i) {
    int m = m0 + ty * 4 + i;
#pragma unroll
    for (int jj = 0; jj < 4; ++jj) {
      int n = n0 + tx * 4 + jj;
      float v = acc[i][jj];
      if (bias) v += bias[n];
      if (addC) v += addC[(size_t)m * ldc + n];
      C[(size_t)m * ldc + n] = v;
    }
  }
}

// ------------------------------ gather -------------------------------------
__global__ void gather_kernel(const float* __restrict__ nodes,
                              const int* __restrict__ edges,
                              float* __restrict__ pair) {
  int t = blockIdx.x;
  int c = threadIdx.x;
  int e = edges[t * 2 + (c >> 8)];
  pair[(size_t)t * 512 + c] = nodes[(size_t)e * 256 + (c & 255)];
}

// --------------------------- fragment prep ---------------------------------
// Whh (f32 [1024][256]) -> f16 MFMA A-fragments.
// Layout (u32x4 units): idx = ((w*16 + rt)*8 + kc)*64 + l
//   row = w*256 + rt*16 + (l&15); k = kc*32 + 8*(l>>4) + e.   [round-6 verified]
struct PrepSrcs { const float* p[9]; };

__global__ __launch_bounds__(256) void prep_frags(PrepSrcs s, u32x4* __restrict__ outAll) {
  int id = blockIdx.x * 256 + threadIdx.x;
  int mat = id >> 15;
  int r   = id & 32767;
  int l   = r & 63;
  int kc  = (r >> 6) & 7;
  int rt  = (r >> 9) & 15;
  int w   = r >> 13;
  const float* W = s.p[mat];
  int row = w * 256 + rt * 16 + (l & 15);
  int kb  = kc * 32 + ((l >> 4) << 3);
  const float* src = W + (size_t)row * 256 + kb;
  uint32_t dw[4];
#pragma unroll
  for (int i = 0; i < 4; ++i) {
    uint16_t lo = __builtin_bit_cast(uint16_t, (_Float16)src[2 * i]);
    uint16_t hi = __builtin_bit_cast(uint16_t, (_Float16)src[2 * i + 1]);
    dw[i] = (uint32_t)lo | ((uint32_t)hi << 16);
  }
  u32x4 v = {dw[0], dw[1], dw[2], dw[3]};
  outAll[id] = v;
}

// ------------------------------ LSTM scan ----------------------------------
struct ScanDesc {
  const float* Xp;        // [T][1024] fp32 input projection (incl. bias)
  const u32x4* Wf;        // fragment buffer (32768 u32x4)
  float* out;             // h output
  int rev;
  int hstride;
};

#define GLD(dst, base, OFF) \
  asm volatile("global_load_dwordx4 %0, %1, off offset:" OFF : "=v"(dst) : "v"(base))

#define SLOAD8(S, BA, BB) \
  GLD(S##_0, BA, "0"); GLD(S##_1, BA, "1024"); GLD(S##_2, BA, "2048"); GLD(S##_3, BA, "3072"); \
  GLD(S##_4, BB, "0"); GLD(S##_5, BB, "1024"); GLD(S##_6, BB, "2048"); GLD(S##_7, BB, "3072");

__global__ __launch_bounds__(256)
__attribute__((amdgpu_waves_per_eu(1, 1)))
void lstm_scan_mfma(ScanDesc d0, ScanDesc d1, ScanDesc d2, int T) {
  ScanDesc d;
  if (blockIdx.x == 0) d = d0;
  else if (blockIdx.x == 1) d = d1;
  else d = d2;
  const float* __restrict__ Xp = d.Xp;
  float* __restrict__ out = d.out;
  const int rev = d.rev, hstride = d.hstride;

  const int j = threadIdx.x;            // 0..255
  const int w = j >> 6, l = j & 63;

  __shared__ __align__(16) u32x4 w_sh[4][4][8][64];   // 128 KiB: tiles 12-15 per wave
  __shared__ __align__(16) float z_sh[1024];
  __shared__ __align__(16) _Float16 h_sh[256];

  const u32x4* fb = d.Wf + (size_t)w * 8192 + l;

  // ---- AGPR tiles 0..7 (256 AGPRs, pinned) — round-6 proven ----
#define AG_DECL(rt, kc) u32x4 A##rt##_##kc = fb[((rt) * 8 + (kc)) * 64];
#define AG_ROW(rt) AG_DECL(rt,0) AG_DECL(rt,1) AG_DECL(rt,2) AG_DECL(rt,3) \
                   AG_DECL(rt,4) AG_DECL(rt,5) AG_DECL(rt,6) AG_DECL(rt,7)
  AG_ROW(0) AG_ROW(1) AG_ROW(2) AG_ROW(3) AG_ROW(4) AG_ROW(5) AG_ROW(6) AG_ROW(7)
#undef AG_ROW
#undef AG_DECL
#define AG_PIN(rt, kc) asm volatile("" : "+a"(A##rt##_##kc));
#define AG_PINR(rt) AG_PIN(rt,0) AG_PIN(rt,1) AG_PIN(rt,2) AG_PIN(rt,3) \
                    AG_PIN(rt,4) AG_PIN(rt,5) AG_PIN(rt,6) AG_PIN(rt,7)
  AG_PINR(0) AG_PINR(1) AG_PINR(2) AG_PINR(3) AG_PINR(4) AG_PINR(5) AG_PINR(6) AG_PINR(7)
#undef AG_PIN
#undef AG_PINR

  // ---- stage tiles 12..15 into LDS (one-time; wave-private slab) ----
#pragma unroll
  for (int rt = 0; rt < 4; ++rt)
#pragma unroll
    for (int kc = 0; kc < 8; ++kc)
      w_sh[w][rt][kc][l] = fb[((12 + rt) * 8 + kc) * 64];

  // ---- stream base pointers for tiles 8..11 (two halves each) ----
  const u32x4* sb8a  = fb + 8  * 512; const u32x4* sb8b  = sb8a  + 256;
  const u32x4* sb9a  = fb + 9  * 512; const u32x4* sb9b  = sb9a  + 256;
  const u32x4* sb10a = fb + 10 * 512; const u32x4* sb10b = sb10a + 256;
  const u32x4* sb11a = fb + 11 * 512; const u32x4* sb11b = sb11a + 256;

  if (j < 128) ((uint32_t*)h_sh)[j] = 0u;
  float c = 0.f;
  const int t0 = rev ? (T - 1) : 0;
  float xpi = Xp[(size_t)t0 * GATE + j];
  float xpf = Xp[(size_t)t0 * GATE + j + 256];
  float xpg = Xp[(size_t)t0 * GATE + j + 512];
  float xpo = Xp[(size_t)t0 * GATE + j + 768];
  __syncthreads();

  const u32x4* wl0 = &w_sh[w][0][0][l];
  uint32_t wofs = 0;                    // opaque 0: blocks LICM of LDS tile reads

  const int zb0 = (w << 8) + ((l >> 4) << 2);
#define ZWt(rt, a) if ((l & 15) == 0) *(f32x4*)&z_sh[zb0 + (rt) * 16] = a;
#define Z4 {0.f,0.f,0.f,0.f}

  for (int s = 0; s < T; ++s) {
    const int t = rev ? (T - 1 - s) : s;

    // ---- issue streamed tiles 8..11 at the very top (latency hidden) ----
    u32x4 S0_0, S0_1, S0_2, S0_3, S0_4, S0_5, S0_6, S0_7;
    u32x4 S1_0, S1_1, S1_2, S1_3, S1_4, S1_5, S1_6, S1_7;
    u32x4 S2_0, S2_1, S2_2, S2_3, S2_4, S2_5, S2_6, S2_7;
    u32x4 S3_0, S3_1, S3_2, S3_3, S3_4, S3_5, S3_6, S3_7;
    SLOAD8(S0, sb8a,  sb8b)
    SLOAD8(S1, sb9a,  sb9b)
    SLOAD8(S2, sb10a, sb10b)
    SLOAD8(S3, sb11a, sb11b)

    // ---- h fragments (B operand, 16 identical cols): 16B broadcast/k-chunk ----
    const char* hbase = (const char*)h_sh + ((l >> 4) << 4);
    u32x4 hb0 = *(const u32x4*)(hbase + 0);
    u32x4 hb1 = *(const u32x4*)(hbase + 64);
    u32x4 hb2 = *(const u32x4*)(hbase + 128);
    u32x4 hb3 = *(const u32x4*)(hbase + 192);
    u32x4 hb4 = *(const u32x4*)(hbase + 256);
    u32x4 hb5 = *(const u32x4*)(hbase + 320);
    u32x4 hb6 = *(const u32x4*)(hbase + 384);
    u32x4 hb7 = *(const u32x4*)(hbase + 448);

    asm volatile("" : "+v"(wofs));
    const u32x4* wlv = wl0 + wofs;
#define WLV(li, kc) wlv[((li) * 8 + (kc)) * 64]

    f32x4 acc0, acc1, acc2, acc3;
#define MAG(t0_,t1_,t2_,t3_,kc) \
    acc0 = mfma16(A##t0_##_##kc, hb##kc, acc0); \
    acc1 = mfma16(A##t1_##_##kc, hb##kc, acc1); \
    acc2 = mfma16(A##t2_##_##kc, hb##kc, acc2); \
    acc3 = mfma16(A##t3_##_##kc, hb##kc, acc3);
#define MAG8(t0_,t1_,t2_,t3_) MAG(t0_,t1_,t2_,t3_,0) MAG(t0_,t1_,t2_,t3_,1) \
    MAG(t0_,t1_,t2_,t3_,2) MAG(t0_,t1_,t2_,t3_,3) MAG(t0_,t1_,t2_,t3_,4) \
    MAG(t0_,t1_,t2_,t3_,5) MAG(t0_,t1_,t2_,t3_,6) MAG(t0_,t1_,t2_,t3_,7)

    // ---- Phase A: AGPR tiles 0-3 ----
    acc0 = (f32x4)Z4; acc1 = (f32x4)Z4; acc2 = (f32x4)Z4; acc3 = (f32x4)Z4;
    MAG8(0,1,2,3)
    ZWt(0, acc0) ZWt(1, acc1) ZWt(2, acc2) ZWt(3, acc3)

    // ---- Phase B: AGPR tiles 4-7 ----
    acc0 = (f32x4)Z4; acc1 = (f32x4)Z4; acc2 = (f32x4)Z4; acc3 = (f32x4)Z4;
    MAG8(4,5,6,7)
    ZWt(4, acc0) ZWt(5, acc1) ZWt(6, acc2) ZWt(7, acc3)
#undef MAG
#undef MAG8

    // ---- Phase C: LDS tiles 12-15 ----
    acc0 = (f32x4)Z4; acc1 = (f32x4)Z4; acc2 = (f32x4)Z4; acc3 = (f32x4)Z4;
#define MLD(kc) \
    acc0 = mfma16(WLV(0,kc), hb##kc, acc0); \
    acc1 = mfma16(WLV(1,kc), hb##kc, acc1); \
    acc2 = mfma16(WLV(2,kc), hb##kc, acc2); \
    acc3 = mfma16(WLV(3,kc), hb##kc, acc3);
    MLD(0) MLD(1) MLD(2) MLD(3) MLD(4) MLD(5) MLD(6) MLD(7)
#undef MLD
    ZWt(12, acc0) ZWt(13, acc1) ZWt(14, acc2) ZWt(15, acc3)
#undef WLV

    // ---- Phase D: streamed tiles 8-11 (single drain, pre-covered) ----
    asm volatile("s_waitcnt vmcnt(0)" ::: "memory");
    __builtin_amdgcn_sched_barrier(0);
    acc0 = (f32x4)Z4; acc1 = (f32x4)Z4; acc2 = (f32x4)Z4; acc3 = (f32x4)Z4;
#define MST(kc) \
    acc0 = mfma16(S0_##kc, hb##kc, acc0); \
    acc1 = mfma16(S1_##kc, hb##kc, acc1); \
    acc2 = mfma16(S2_##kc, hb##kc, acc2); \
    acc3 = mfma16(S3_##kc, hb##kc, acc3);
    MST(0) MST(1) MST(2) MST(3) MST(4) MST(5) MST(6) MST(7)
#undef MST
    ZWt(8, acc0) ZWt(9, acc1) ZWt(10, acc2) ZWt(11, acc3)

    __syncthreads();

    // ---- gate phase (all 256 threads; j = hidden unit) ----
    {
      float zi = z_sh[j]       + xpi;
      float zf = z_sh[j + 256] + xpf;
      float zg = z_sh[j + 512] + xpg;
      float zo = z_sh[j + 768] + xpo;
      float ig = fsig(zi), fg = fsig(zf), gg = ftanh(zg), og = fsig(zo);
      c = fg * c + ig * gg;
      float h = og * ftanh(c);
      out[(size_t)t * hstride + j] = h;
      h_sh[j] = (_Float16)h;
      int sn = (s + 1 < T) ? (s + 1) : s;
      int tn = rev ? (T - 1 - sn) : sn;
      xpi = Xp[(size_t)tn * GATE + j];
      xpf = Xp[(size_t)tn * GATE + j + 256];
      xpg = Xp[(size_t)tn * GATE + j + 512];
      xpo = Xp[(size_t)tn * GATE + j + 768];
    }
    __syncthreads();
  }
#undef ZWt
#undef Z4
}

// ---------------------------------------------------------------------------
extern "C" void kernel_launch(void* const* d_in, const int* in_sizes, int n_in,
                              void* d_out, int out_size, void* d_ws, size_t ws_size,
                              hipStream_t stream) {
  (void)in_sizes; (void)n_in; (void)out_size; (void)ws_size;
  const float* inputs = (const float*)d_in[0];
  const int*   edges  = (const int*)d_in[1];
  const float* memory = (const float*)d_in[2];
  const float* Wl_ih  = (const float*)d_in[3];
  const float* Wl_hh  = (const float*)d_in[4];
  const float* bl     = (const float*)d_in[5];
  const float* Wh_ih  = (const float*)d_in[6];
  const float* Wh_hh  = (const float*)d_in[7];
  const float* bh     = (const float*)d_in[8];
  const float* Win    = (const float*)d_in[9];
  const float* bin_   = (const float*)d_in[10];
  const float* We     = (const float*)d_in[11];
  const float* be     = (const float*)d_in[12];
  const float* Wn_ih  = (const float*)d_in[13];
  const float* Wn_hh  = (const float*)d_in[14];
  const float* bn     = (const float*)d_in[15];
  const float* Wmem   = (const float*)d_in[16];
  const float* bmem   = (const float*)d_in[17];
  const float* Wc_ih  = (const float*)d_in[18];
  const float* Wc_hh  = (const float*)d_in[19];
  const float* bc     = (const float*)d_in[20];
  const float* Wout   = (const float*)d_in[21];
  const float* bout   = (const float*)d_in[22];

  float* out_ptr = (float*)d_out;                       // [T][256]
  float* memvec  = out_ptr + (size_t)T_LEN * OUT_N;     // [T][256]

  // ---- workspace carve ----
  char* base = (char*)d_ws;
  size_t off = 0;
  auto carve = [&](size_t nbytes) -> void* {
    void* p = base + off; off += (nbytes + 255) & ~(size_t)255; return p;
  };
  float* XpA    = (float*)carve((size_t)T_LEN * GATE * 4);
  float* XpB    = (float*)carve((size_t)T_LEN * GATE * 4);
  float* XpC    = (float*)carve((size_t)T_LEN * GATE * 4);
  float* XpN    = (float*)carve((size_t)T_LEN * GATE * 4);
  float* lower  = (float*)carve((size_t)T_LEN * 512 * 4);
  float* higher = (float*)carve((size_t)T_LEN * 512 * 4);
  float* nodesA = (float*)carve((size_t)T_LEN * 256 * 4);
  float* nodesB = (float*)carve((size_t)T_LEN * 256 * 4);
  float* pairb  = (float*)carve((size_t)T_LEN * 512 * 4);
  float* ehb    = (float*)carve((size_t)T_LEN * 256 * 4);
  float* ctrlh  = (float*)carve((size_t)T_LEN * 256 * 4);
  u32x4* Wf_all = (u32x4*)carve((size_t)9 * 32768 * 16);

  // ---- fragment prep (9 recurrent matrices) ----
  PrepSrcs ps;
  ps.p[0] = Wl_hh;            ps.p[1] = Wl_hh + 262144;
  ps.p[2] = Wh_hh;            ps.p[3] = Wh_hh + 262144;
  ps.p[4] = Wn_hh;            ps.p[5] = Wn_hh + 262144;
  ps.p[6] = Wn_hh + 524288;   ps.p[7] = Wn_hh + 786432;
  ps.p[8] = Wc_hh;
  prep_frags<<<9 * 32768 / 256, 256, 0, stream>>>(ps, Wf_all);
  auto Wf = [&](int m) { return (const u32x4*)(Wf_all + (size_t)m * 32768); };

  auto gemm = [&](float* C, int ldc, const float* A, int lda,
                  const float* W, int ldw, const float* bias, const float* addC,
                  int M, int N, int K) {
    dim3 g(N / 64, M / 64);
    gemm_kernel<<<g, 256, 0, stream>>>(A, lda, W, ldw, bias, addC, C, ldc, M, N, K);
  };
  auto scan3 = [&](ScanDesc a, ScanDesc b, ScanDesc c, int nblk) {
    lstm_scan_mfma<<<nblk, 256, 0, stream>>>(a, b, c, T_LEN);
  };
  ScanDesc dummy = {};

  // ---- G0: lower Xp + node0 Xp ----
  gemm(XpA, GATE, inputs, IN_F, Wl_ih,               IN_F, bl,        nullptr, T_LEN, GATE, IN_F);
  gemm(XpB, GATE, inputs, IN_F, Wl_ih + GATE * IN_F, IN_F, bl + GATE, nullptr, T_LEN, GATE, IN_F);
  gemm(nodesA, 256, inputs, IN_F, Win, IN_F, bin_, nullptr, T_LEN, 256, IN_F);
  gather_kernel<<<T_LEN, 512, 0, stream>>>(nodesA, edges, pairb);
  gemm(ehb, 256, pairb, 512, We + (size_t)0 * HID * 512, 512, be + 0 * HID, nullptr, T_LEN, 256, 512);
  gemm(XpN, GATE, inputs, IN_F, Wn_ih + (size_t)0 * GATE * 512,       512, bn + 0 * GATE, nullptr, T_LEN, GATE, IN_F);
  gemm(XpN, GATE, ehb,    256,  Wn_ih + (size_t)0 * GATE * 512 + 256, 512, nullptr,       XpN,     T_LEN, GATE, 256);

  // ---- Slot1: lower fwd/bwd + node0 ----
  scan3({XpA, Wf(0), lower,       0, 512},
        {XpB, Wf(1), lower + 256, 1, 512},
        {XpN, Wf(4), nodesB,      0, 256}, 3);

  // ---- G1: higher Xp + node1 Xp ----
  gemm(XpA, GATE, lower, 512, Wh_ih,              512, bh,        nullptr, T_LEN, GATE, 512);
  gemm(XpB, GATE, lower, 512, Wh_ih + GATE * 512, 512, bh + GATE, nullptr, T_LEN, GATE, 512);
  gather_kernel<<<T_LEN, 512, 0, stream>>>(nodesB, edges, pairb);
  gemm(ehb, 256, pairb, 512, We + (size_t)1 * HID * 512, 512, be + 1 * HID, nullptr, T_LEN, 256, 512);
  gemm(XpN, GATE, inputs, IN_F, Wn_ih + (size_t)1 * GATE * 512,       512, bn + 1 * GATE, nullptr, T_LEN, GATE, IN_F);
  gemm(XpN, GATE, ehb,    256,  Wn_ih + (size_t)1 * GATE * 512 + 256, 512, nullptr,       XpN,     T_LEN, GATE, 256);

  // ---- Slot2: higher fwd/bwd + node1 ----
  scan3({XpA, Wf(2), higher,       0, 512},
        {XpB, Wf(3), higher + 256, 1, 512},
        {XpN, Wf(5), nodesA,       0, 256}, 3);

  // ---- G2: ctrl Xp + node2 Xp ----
  gemm(XpC, GATE, inputs, IN_F, Wc_ih,       896, bc,      nullptr, T_LEN, GATE, IN_F);
  gemm(XpC, GATE, memory, 128,  Wc_ih + 768, 896, nullptr, XpC,     T_LEN, GATE, 128);
  gemm(XpC, GATE, higher, 512,  Wc_ih + 256, 896, nullptr, XpC,     T_LEN, GATE, 512);
  gather_kernel<<<T_LEN, 512, 0, stream>>>(nodesA, edges, pairb);
  gemm(ehb, 256, pairb, 512, We + (size_t)2 * HID * 512, 512, be + 2 * HID, nullptr, T_LEN, 256, 512);
  gemm(XpN, GATE, inputs, IN_F, Wn_ih + (size_t)2 * GATE * 512,       512, bn + 2 * GATE, nullptr, T_LEN, GATE, IN_F);
  gemm(XpN, GATE, ehb,    256,  Wn_ih + (size_t)2 * GATE * 512 + 256, 512, nullptr,       XpN,     T_LEN, GATE, 256);

  // ---- Slot3: node2 + ctrl ----
  scan3({XpN, Wf(6), nodesB, 0, 256},
        {XpC, Wf(8), ctrlh,  0, 256}, dummy, 2);

  // ---- G3: node3 Xp ----
  gather_kernel<<<T_LEN, 512, 0, stream>>>(nodesB, edges, pairb);
  gemm(ehb, 256, pairb, 512, We + (size_t)3 * HID * 512, 512, be + 3 * HID, nullptr, T_LEN, 256, 512);
  gemm(XpN, GATE, inputs, IN_F, Wn_ih + (size_t)3 * GATE * 512,       512, bn + 3 * GATE, nullptr, T_LEN, GATE, IN_F);
  gemm(XpN, GATE, ehb,    256,  Wn_ih + (size_t)3 * GATE * 512 + 256, 512, nullptr,       XpN,     T_LEN, GATE, 256);

  // ---- Slot4: node3 ----
  scan3({XpN, Wf(7), nodesA, 0, 256}, dummy, dummy, 1);

  // ---- finals ----
  gemm(memvec,  256, nodesA, 256, Wmem, HID, bmem, nullptr, T_LEN, 256, HID);
  gemm(out_ptr, 256, ctrlh,  256, Wout, HID, bout, nullptr, T_LEN, 256, HID);
}

// Round 9
// 64005.249 us; speedup vs baseline: 1.5478x; 1.5478x over previous
//
#include <hip/hip_runtime.h>
#include <cstdint>

// ---------------------------------------------------------------------------
// HierarchicalGraphMemoryNetwork on MI355X — round 9
//
//  - Scan: revert to round-5 v_dot2 kernel (best measured: ~12-15ms/slot).
//    Rounds 6-8 (MFMA scan) were structurally worse: replicated-column MFMA
//    wastes 16x FLOPs (2400cy floor vs v_dot2's 1024cy) and 1 wave/SIMD
//    exposed all latencies. The scan sits near the 512KB/CU register-file
//    wall; further gains there are ~30% at high risk.
//  - NEW: bf16 MFMA GEMM (gemm16_kernel) for all input-projection GEMMs
//    (~85 GF that cost ~15ms on the fp32 vector kernel). f32->bf16 RTN
//    conversion happens during LDS staging; XOR-swizzled LDS both sides;
//    fragment layouts per m89-verified mapping. Output-facing finals stay
//    fp32.
// ---------------------------------------------------------------------------

#define T_LEN 8192
#define IN_F  256
#define HID   256
#define GATE  1024
#define NREL  4
#define OUT_N 256

typedef _Float16 half2_t __attribute__((ext_vector_type(2)));
typedef float    f32x4  __attribute__((ext_vector_type(4)));
typedef uint32_t u32x4  __attribute__((ext_vector_type(4)));
typedef short    s16x8  __attribute__((ext_vector_type(8)));

__device__ __forceinline__ float fdot2(uint32_t w, uint32_t h, float acc) {
#if __has_builtin(__builtin_amdgcn_fdot2)
  return __builtin_amdgcn_fdot2(__builtin_bit_cast(half2_t, w),
                                __builtin_bit_cast(half2_t, h), acc, false);
#else
  asm("v_dot2_f32_f16 %0, %1, %2, %0" : "+v"(acc) : "v"(w), "v"(h));
  return acc;
#endif
}

__device__ __forceinline__ float fsig(float x) { return 1.f / (1.f + __expf(-x)); }
__device__ __forceinline__ float ftanh(float x) { return 2.f / (1.f + __expf(-2.f * x)) - 1.f; }

__device__ __forceinline__ uint32_t pack2bf(float x, float y) {
  uint32_t ux = __builtin_bit_cast(uint32_t, x);
  uint32_t uy = __builtin_bit_cast(uint32_t, y);
  uint32_t rx = (ux + 0x7FFFu + ((ux >> 16) & 1u)) >> 16;
  uint32_t ry = (uy + 0x7FFFu + ((uy >> 16) & 1u)) >> 16;
  return (rx & 0xFFFFu) | (ry << 16);
}

__device__ __forceinline__ f32x4 mfma_bf(u32x4 a, u32x4 b, f32x4 c) {
  return __builtin_amdgcn_mfma_f32_16x16x32_bf16(
      __builtin_bit_cast(s16x8, a), __builtin_bit_cast(s16x8, b), c, 0, 0, 0);
}

// -------------------------- fp32 -> f16 convert ----------------------------
__global__ void f2h_kernel(const float* __restrict__ in, _Float16* __restrict__ out, int n) {
  int i = blockIdx.x * blockDim.x + threadIdx.x;
  if (i < n) out[i] = (_Float16)in[i];
}

// --------------------------- bf16 MFMA GEMM --------------------------------
// C[M][N] = A[M][K] @ W[N][K]^T (+bias[N]) (+addC); BM=BN=64, BK=32.
// 256 thr = 4 waves; wave w owns rows m0+16w..+15, all 64 cols (4 col-tiles).
// LDS tiles [64 rows][32 bf16] = 64B/row; 16B slot s of row r stored at
// byte (r*64 + s*16) ^ ((r&3)<<4)  — same map on write & read (2-way max).
__global__ __launch_bounds__(256) void gemm16_kernel(
    const float* __restrict__ A, int lda,
    const float* __restrict__ W, int ldw,
    const float* __restrict__ bias, const float* addC,
    float* C, int ldc, int K) {
  __shared__ __align__(16) char As[4096];
  __shared__ __align__(16) char Bs[4096];
  const int tid = threadIdx.x;
  const int w = tid >> 6, l = tid & 63;
  const int m0 = blockIdx.y * 64, n0 = blockIdx.x * 64;

  const int srow = tid >> 2, skq = tid & 3;                  // staging: row, 16B slot
  const int sbyte = (srow * 64 + skq * 16) ^ ((srow & 3) << 4);
  const float* Ap = A + (size_t)(m0 + srow) * lda + skq * 8;
  const float* Wp = W + (size_t)(n0 + srow) * ldw + skq * 8;

  const int fr = l & 15, kb = l >> 4;                        // fragment: row-in-tile, k-octet
  const int ar = w * 16 + fr;
  const int abyte  = (ar * 64 + kb * 16) ^ ((ar & 3) << 4);
  const int bbyte0 = ((fr)      * 64 + kb * 16) ^ ((fr & 3) << 4);
  const int bbyte1 = ((16 + fr) * 64 + kb * 16) ^ ((fr & 3) << 4);
  const int bbyte2 = ((32 + fr) * 64 + kb * 16) ^ ((fr & 3) << 4);
  const int bbyte3 = ((48 + fr) * 64 + kb * 16) ^ ((fr & 3) << 4);

  f32x4 acc0 = {0.f,0.f,0.f,0.f}, acc1 = {0.f,0.f,0.f,0.f};
  f32x4 acc2 = {0.f,0.f,0.f,0.f}, acc3 = {0.f,0.f,0.f,0.f};

  for (int k0 = 0; k0 < K; k0 += 32) {
    float4 a0 = *(const float4*)(Ap + k0);
    float4 a1 = *(const float4*)(Ap + k0 + 4);
    float4 w0 = *(const float4*)(Wp + k0);
    float4 w1 = *(const float4*)(Wp + k0 + 4);
    u32x4 pa = {pack2bf(a0.x,a0.y), pack2bf(a0.z,a0.w), pack2bf(a1.x,a1.y), pack2bf(a1.z,a1.w)};
    u32x4 pb = {pack2bf(w0.x,w0.y), pack2bf(w0.z,w0.w), pack2bf(w1.x,w1.y), pack2bf(w1.z,w1.w)};
    *(u32x4*)(As + sbyte) = pa;
    *(u32x4*)(Bs + sbyte) = pb;
    __syncthreads();
    u32x4 af  = *(const u32x4*)(As + abyte);
    u32x4 bf0 = *(const u32x4*)(Bs + bbyte0);
    u32x4 bf1 = *(const u32x4*)(Bs + bbyte1);
    u32x4 bf2 = *(const u32x4*)(Bs + bbyte2);
    u32x4 bf3 = *(const u32x4*)(Bs + bbyte3);
    acc0 = mfma_bf(af, bf0, acc0);
    acc1 = mfma_bf(af, bf1, acc1);
    acc2 = mfma_bf(af, bf2, acc2);
    acc3 = mfma_bf(af, bf3, acc3);
    __syncthreads();
  }

  // D layout (m89): col = lane&15, row = (lane>>4)*4 + reg
  const int col = l & 15;
  const int rb  = (l >> 4) * 4;
#define EPI(ct, ACC) { \
    int n = n0 + (ct) * 16 + col; \
    float bv = bias ? bias[n] : 0.f; \
    _Pragma("unroll") \
    for (int r = 0; r < 4; ++r) { \
      int m = m0 + w * 16 + rb + r; \
      float v = ACC[r] + bv; \
      if (addC) v += addC[(size_t)m * ldc + n]; \
      C[(size_t)m * ldc + n] = v; } }
  EPI(0, acc0) EPI(1, acc1) EPI(2, acc2) EPI(3, acc3)
#undef EPI
}

// ------------------------- fp32 GEMM (finals only) -------------------------
__global__ __launch_bounds__(256) void gemm_kernel(
    const float* __restrict__ A, int lda,
    const float* __restrict__ W, int ldw,
    const float* __restrict__ bias,
    const float* addC,
    float* C, int ldc, int M, int N, int K) {
  __shared__ float As[16][64];
  __shared__ float Bs[16][64];
  const int tid = threadIdx.x;
  const int tx = tid & 15, ty = tid >> 4;
  const int m0 = blockIdx.y * 64, n0 = blockIdx.x * 64;
  const int lr = tid >> 2;
  const int lc = (tid & 3) * 4;
  float acc[4][4] = {};
  for (int k0 = 0; k0 < K; k0 += 16) {
    float4 av = *(const float4*)&A[(size_t)(m0 + lr) * lda + k0 + lc];
    float4 wv = *(const float4*)&W[(size_t)(n0 + lr) * ldw + k0 + lc];
    As[lc + 0][lr] = av.x; As[lc + 1][lr] = av.y; As[lc + 2][lr] = av.z; As[lc + 3][lr] = av.w;
    Bs[lc + 0][lr] = wv.x; Bs[lc + 1][lr] = wv.y; Bs[lc + 2][lr] = wv.z; Bs[lc + 3][lr] = wv.w;
    __syncthreads();
#pragma unroll
    for (int k = 0; k < 16; ++k) {
      float a[4], b[4];
#pragma unroll
      for (int i = 0; i < 4; ++i) a[i] = As[k][ty * 4 + i];
#pragma unroll
      for (int jj = 0; jj < 4; ++jj) b[jj] = Bs[k][tx * 4 + jj];
#pragma unroll
      for (int i = 0; i < 4; ++i)
#pragma unroll
        for (int jj = 0; jj < 4; ++jj) acc[i][jj] += a[i] * b[jj];
    }
    __syncthreads();
  }
#pragma unroll
  for (int i = 0; i < 4; ++i) {
    int m = m0 + ty * 4 + i;
#pragma unroll
    for (int jj = 0; jj < 4; ++jj) {
      int n = n0 + tx * 4 + jj;
      float v = acc[i][jj];
      if (bias) v += bias[n];
      if (addC) v += addC[(size_t)m * ldc + n];
      C[(size_t)m * ldc + n] = v;
    }
  }
}

// ------------------------------ gather -------------------------------------
__global__ void gather_kernel(const float* __restrict__ nodes,
                              const int* __restrict__ edges,
                              float* __restrict__ pair) {
  int t = blockIdx.x;
  int c = threadIdx.x;              // 0..511
  int e = edges[t * 2 + (c >> 8)];
  pair[(size_t)t * 512 + c] = nodes[(size_t)e * 256 + (c & 255)];
}

// ------------------------------ LSTM scan ----------------------------------
// Round-5 kernel verbatim: 512 threads, 2 waves/SIMD; thread j owns gate rows
// j and j+512; dwords 0..95/row in named regs, 96..127 in 128KiB LDS tile.
struct ScanDesc {
  const float* Xp;
  const uint32_t* W;
  float* out;
  int rev;
  int hstride;
};

#define FOR24(M) M(0) M(1) M(2) M(3) M(4) M(5) M(6) M(7) M(8) M(9) M(10) M(11) \
                 M(12) M(13) M(14) M(15) M(16) M(17) M(18) M(19) M(20) M(21) M(22) M(23)

__global__
__attribute__((amdgpu_flat_work_group_size(512, 512), amdgpu_waves_per_eu(2)))
void lstm_scan2(ScanDesc d0, ScanDesc d1, ScanDesc d2, int T) {
  ScanDesc d;
  if (blockIdx.x == 0) d = d0;
  else if (blockIdx.x == 1) d = d1;
  else d = d2;
  const float* __restrict__ Xp = d.Xp;
  const uint32_t* __restrict__ W = d.W;
  float* __restrict__ out = d.out;
  const int rev = d.rev, hstride = d.hstride;

  const int j = threadIdx.x;                 // 0..511
  __shared__ uint4 w_lds[2][8][512];         // 128 KiB
  __shared__ float z_lds[1024];
  __shared__ uint32_t h_lds[128];            // 256 f16

  const uint4* wrow0 = (const uint4*)(W + (size_t)j * 128);
  const uint4* wrow1 = (const uint4*)(W + (size_t)(j + 512) * 128);

#define DECLW(i) uint4 wa##i, wb##i;
  FOR24(DECLW)
#undef DECLW
#define LOADW(i) wa##i = wrow0[i]; wb##i = wrow1[i];
  FOR24(LOADW)
#undef LOADW

#pragma unroll
  for (int q = 0; q < 8; ++q) w_lds[0][q][j] = wrow0[24 + q];
#pragma unroll
  for (int q = 0; q < 8; ++q) w_lds[1][q][j] = wrow1[24 + q];
  if (j < 128) h_lds[j] = 0u;
  float c = 0.f;
  __syncthreads();

  const int t0 = rev ? (T - 1) : 0;
  float xp0 = Xp[(size_t)t0 * GATE + j];
  float xp1 = Xp[(size_t)t0 * GATE + j + 512];

  for (int s = 0; s < T; ++s) {
    const int t = rev ? (T - 1 - s) : s;
    float a0 = xp0, a1 = 0.f, a2 = 0.f, a3 = 0.f;
    float b0 = xp1, b1 = 0.f, b2 = 0.f, b3 = 0.f;
    if (s + 1 < T) {
      const int tn = rev ? (t - 1) : (t + 1);
      xp0 = Xp[(size_t)tn * GATE + j];
      xp1 = Xp[(size_t)tn * GATE + j + 512];
    }

    const uint4* hq = (const uint4*)h_lds;
#define DOTQ(i) { uint4 hv = hq[i];                                   \
      a0 = fdot2(wa##i.x, hv.x, a0); b0 = fdot2(wb##i.x, hv.x, b0);   \
      a1 = fdot2(wa##i.y, hv.y, a1); b1 = fdot2(wb##i.y, hv.y, b1);   \
      a2 = fdot2(wa##i.z, hv.z, a2); b2 = fdot2(wb##i.z, hv.z, b2);   \
      a3 = fdot2(wa##i.w, hv.w, a3); b3 = fdot2(wb##i.w, hv.w, b3); }
    FOR24(DOTQ)
#undef DOTQ
#pragma unroll
    for (int q = 0; q < 8; ++q) {
      uint4 hv = hq[24 + q];
      uint4 wa = w_lds[0][q][j], wb = w_lds[1][q][j];
      a0 = fdot2(wa.x, hv.x, a0); b0 = fdot2(wb.x, hv.x, b0);
      a1 = fdot2(wa.y, hv.y, a1); b1 = fdot2(wb.y, hv.y, b1);
      a2 = fdot2(wa.z, hv.z, a2); b2 = fdot2(wb.z, hv.z, b2);
      a3 = fdot2(wa.w, hv.w, a3); b3 = fdot2(wb.w, hv.w, b3);
    }
    z_lds[j] = (a0 + a1) + (a2 + a3);
    z_lds[j + 512] = (b0 + b1) + (b2 + b3);
    __syncthreads();

    if (j < HID) {
      float zi = z_lds[j], zf = z_lds[j + 256], zg = z_lds[j + 512], zo = z_lds[j + 768];
      float ig = fsig(zi), fg = fsig(zf), gg = ftanh(zg), og = fsig(zo);
      c = fg * c + ig * gg;
      float h = og * ftanh(c);
      out[(size_t)t * hstride + j] = h;
      ((_Float16*)h_lds)[j] = (_Float16)h;
    }
    __syncthreads();
  }
}

// ---------------------------------------------------------------------------
extern "C" void kernel_launch(void* const* d_in, const int* in_sizes, int n_in,
                              void* d_out, int out_size, void* d_ws, size_t ws_size,
                              hipStream_t stream) {
  (void)in_sizes; (void)n_in; (void)out_size; (void)ws_size;
  const float* inputs = (const float*)d_in[0];
  const int*   edges  = (const int*)d_in[1];
  const float* memory = (const float*)d_in[2];
  const float* Wl_ih  = (const float*)d_in[3];
  const float* Wl_hh  = (const float*)d_in[4];
  const float* bl     = (const float*)d_in[5];
  const float* Wh_ih  = (const float*)d_in[6];
  const float* Wh_hh  = (const float*)d_in[7];
  const float* bh     = (const float*)d_in[8];
  const float* Win    = (const float*)d_in[9];
  const float* bin_   = (const float*)d_in[10];
  const float* We     = (const float*)d_in[11];
  const float* be     = (const float*)d_in[12];
  const float* Wn_ih  = (const float*)d_in[13];
  const float* Wn_hh  = (const float*)d_in[14];
  const float* bn     = (const float*)d_in[15];
  const float* Wmem   = (const float*)d_in[16];
  const float* bmem   = (const float*)d_in[17];
  const float* Wc_ih  = (const float*)d_in[18];
  const float* Wc_hh  = (const float*)d_in[19];
  const float* bc     = (const float*)d_in[20];
  const float* Wout   = (const float*)d_in[21];
  const float* bout   = (const float*)d_in[22];

  float* out_ptr = (float*)d_out;                       // [T][256]
  float* memvec  = out_ptr + (size_t)T_LEN * OUT_N;     // [T][256]

  // ---- workspace carve ----
  char* base = (char*)d_ws;
  size_t off = 0;
  auto carve = [&](size_t nbytes) -> void* {
    void* p = base + off; off += (nbytes + 255) & ~(size_t)255; return p;
  };
  float* XpA    = (float*)carve((size_t)T_LEN * GATE * 4);
  float* XpB    = (float*)carve((size_t)T_LEN * GATE * 4);
  float* XpC    = (float*)carve((size_t)T_LEN * GATE * 4);
  float* XpN    = (float*)carve((size_t)T_LEN * GATE * 4);
  float* lower  = (float*)carve((size_t)T_LEN * 512 * 4);
  float* higher = (float*)carve((size_t)T_LEN * 512 * 4);
  float* nodesA = (float*)carve((size_t)T_LEN * 256 * 4);
  float* nodesB = (float*)carve((size_t)T_LEN * 256 * 4);
  float* pairb  = (float*)carve((size_t)T_LEN * 512 * 4);
  float* ehb    = (float*)carve((size_t)T_LEN * 256 * 4);
  float* ctrlh  = (float*)carve((size_t)T_LEN * 256 * 4);
  uint32_t* Wl16 = (uint32_t*)carve((size_t)2 * GATE * HID * 2);
  uint32_t* Wh16 = (uint32_t*)carve((size_t)2 * GATE * HID * 2);
  uint32_t* Wn16 = (uint32_t*)carve((size_t)4 * GATE * HID * 2);
  uint32_t* Wc16 = (uint32_t*)carve((size_t)1 * GATE * HID * 2);
  const size_t WMAT = (size_t)GATE * HID / 2;

  auto f2h = [&](const float* src, uint32_t* dst, int n) {
    f2h_kernel<<<(n + 255) / 256, 256, 0, stream>>>(src, (_Float16*)dst, n);
  };
  f2h(Wl_hh, Wl16, 2 * GATE * HID);
  f2h(Wh_hh, Wh16, 2 * GATE * HID);
  f2h(Wn_hh, Wn16, 4 * GATE * HID);
  f2h(Wc_hh, Wc16, 1 * GATE * HID);

  // bf16 MFMA GEMM (input projections & graph GEMMs)
  auto gemm16 = [&](float* C, int ldc, const float* A, int lda,
                    const float* W, int ldw, const float* bias, const float* addC,
                    int M, int N, int K) {
    dim3 g(N / 64, M / 64);
    gemm16_kernel<<<g, 256, 0, stream>>>(A, lda, W, ldw, bias, addC, C, ldc, K);
  };
  // fp32 GEMM (output-facing finals)
  auto gemm = [&](float* C, int ldc, const float* A, int lda,
                  const float* W, int ldw, const float* bias, const float* addC,
                  int M, int N, int K) {
    dim3 g(N / 64, M / 64);
    gemm_kernel<<<g, 256, 0, stream>>>(A, lda, W, ldw, bias, addC, C, ldc, M, N, K);
  };
  auto scan3 = [&](ScanDesc a, ScanDesc b, ScanDesc c, int nblk) {
    lstm_scan2<<<nblk, 512, 0, stream>>>(a, b, c, T_LEN);
  };
  ScanDesc dummy = {};

  // ---- G0: lower Xp + node0 Xp ----
  gemm16(XpA, GATE, inputs, IN_F, Wl_ih,               IN_F, bl,        nullptr, T_LEN, GATE, IN_F);
  gemm16(XpB, GATE, inputs, IN_F, Wl_ih + GATE * IN_F, IN_F, bl + GATE, nullptr, T_LEN, GATE, IN_F);
  gemm16(nodesA, 256, inputs, IN_F, Win, IN_F, bin_, nullptr, T_LEN, 256, IN_F);
  gather_kernel<<<T_LEN, 512, 0, stream>>>(nodesA, edges, pairb);
  gemm16(ehb, 256, pairb, 512, We + (size_t)0 * HID * 512, 512, be + 0 * HID, nullptr, T_LEN, 256, 512);
  gemm16(XpN, GATE, inputs, IN_F, Wn_ih + (size_t)0 * GATE * 512,       512, bn + 0 * GATE, nullptr, T_LEN, GATE, IN_F);
  gemm16(XpN, GATE, ehb,    256,  Wn_ih + (size_t)0 * GATE * 512 + 256, 512, nullptr,       XpN,     T_LEN, GATE, 256);

  // ---- Slot1: lower fwd/bwd + node0 ----
  scan3({XpA, Wl16,        lower,       0, 512},
        {XpB, Wl16 + WMAT, lower + 256, 1, 512},
        {XpN, Wn16,        nodesB,      0, 256}, 3);

  // ---- G1: higher Xp + node1 Xp ----
  gemm16(XpA, GATE, lower, 512, Wh_ih,              512, bh,        nullptr, T_LEN, GATE, 512);
  gemm16(XpB, GATE, lower, 512, Wh_ih + GATE * 512, 512, bh + GATE, nullptr, T_LEN, GATE, 512);
  gather_kernel<<<T_LEN, 512, 0, stream>>>(nodesB, edges, pairb);
  gemm16(ehb, 256, pairb, 512, We + (size_t)1 * HID * 512, 512, be + 1 * HID, nullptr, T_LEN, 256, 512);
  gemm16(XpN, GATE, inputs, IN_F, Wn_ih + (size_t)1 * GATE * 512,       512, bn + 1 * GATE, nullptr, T_LEN, GATE, IN_F);
  gemm16(XpN, GATE, ehb,    256,  Wn_ih + (size_t)1 * GATE * 512 + 256, 512, nullptr,       XpN,     T_LEN, GATE, 256);

  // ---- Slot2: higher fwd/bwd + node1 ----
  scan3({XpA, Wh16,        higher,       0, 512},
        {XpB, Wh16 + WMAT, higher + 256, 1, 512},
        {XpN, Wn16 + WMAT, nodesA,       0, 256}, 3);

  // ---- G2: ctrl Xp + node2 Xp ----
  gemm16(XpC, GATE, inputs, IN_F, Wc_ih,       896, bc,      nullptr, T_LEN, GATE, IN_F);
  gemm16(XpC, GATE, memory, 128,  Wc_ih + 768, 896, nullptr, XpC,     T_LEN, GATE, 128);
  gemm16(XpC, GATE, higher, 512,  Wc_ih + 256, 896, nullptr, XpC,     T_LEN, GATE, 512);
  gather_kernel<<<T_LEN, 512, 0, stream>>>(nodesA, edges, pairb);
  gemm16(ehb, 256, pairb, 512, We + (size_t)2 * HID * 512, 512, be + 2 * HID, nullptr, T_LEN, 256, 512);
  gemm16(XpN, GATE, inputs, IN_F, Wn_ih + (size_t)2 * GATE * 512,       512, bn + 2 * GATE, nullptr, T_LEN, GATE, IN_F);
  gemm16(XpN, GATE, ehb,    256,  Wn_ih + (size_t)2 * GATE * 512 + 256, 512, nullptr,       XpN,     T_LEN, GATE, 256);

  // ---- Slot3: node2 + ctrl ----
  scan3({XpN, Wn16 + 2 * WMAT, nodesB, 0, 256},
        {XpC, Wc16,            ctrlh,  0, 256}, dummy, 2);

  // ---- G3: node3 Xp ----
  gather_kernel<<<T_LEN, 512, 0, stream>>>(nodesB, edges, pairb);
  gemm16(ehb, 256, pairb, 512, We + (size_t)3 * HID * 512, 512, be + 3 * HID, nullptr, T_LEN, 256, 512);
  gemm16(XpN, GATE, inputs, IN_F, Wn_ih + (size_t)3 * GATE * 512,       512, bn + 3 * GATE, nullptr, T_LEN, GATE, IN_F);
  gemm16(XpN, GATE, ehb,    256,  Wn_ih + (size_t)3 * GATE * 512 + 256, 512, nullptr,       XpN,     T_LEN, GATE, 256);

  // ---- Slot4: node3 ----
  scan3({XpN, Wn16 + 3 * WMAT, nodesA, 0, 256}, dummy, dummy, 1);

  // ---- finals (fp32 for output precision) ----
  gemm(memvec,  256, nodesA, 256, Wmem, HID, bmem, nullptr, T_LEN, 256, HID);
  gemm(out_ptr, 256, ctrlh,  256, Wout, HID, bout, nullptr, T_LEN, 256, HID);
}